// Round 7
// baseline (108.022 us; speedup 1.0000x reference)
//
#include <hip/hip_runtime.h>

#define OUT_H 512
#define OUT_W 512
#define BATCH 64
#define CHANS 3

#define WROWS 46
#define WPX   46
#define RDW   138            // data dwords per row (46 px * 3 ch)
#define PITCH 139            // LDS row pitch in dwords; odd (139%32=11) -> all banks in every rotation regime
#define LSZ   (WROWS * PITCH)   // 6394 dwords = 25576 B -> 6 blocks/CU
#define IDXMAX 6249          // max read = IDXMAX+PITCH+5 = 6393 < LSZ

__global__ __launch_bounds__(256) void st_bilinear_kernel(
    const float* __restrict__ U,      // [B, H, W, C] f32
    const float* __restrict__ theta,  // [B, 1]
    float* __restrict__ out)          // [B, H, W, C] f32
{
    __shared__ float smf[LSZ];

    // XCD-aware remap: give XCD k images [k*8, k*8+8) so each 3.1 MB image
    // stays resident in one XCD's 4 MB L2.
    int blk  = blockIdx.x;
    int lblk = (blk & 7) * 2048 + (blk >> 3);

    int b  = lblk >> 8;                 // image (uniform per block)
    int t  = lblk & 255;                // 16x16 tiles of 32x32 px
    int i0 = (t >> 4) << 5;
    int j0 = (t & 15) << 5;

    int tid = threadIdx.x;

    float tt = theta[__builtin_amdgcn_readfirstlane(b)];
    float s, c;
    __sincosf(tt, &s, &c);

    // x = xb0 + c*jl - s*il ; y = yb0 + s*jl + c*il  ((2/511)*255.5 == 1)
    const float scale = 2.0f / 511.0f;
    float gx0 = (float)j0 * scale - 1.0f;
    float gy0 = (float)i0 * scale - 1.0f;
    float xb0 = (c * gx0 - s * gy0 + 1.0f) * 255.5f;
    float yb0 = (s * gx0 + c * gy0 + 1.0f) * 255.5f;

    // Source bbox of the 32x32 tile. Width 31(|c|+|s|) <= 43.85 -> x1 span
    // fits in 46 px starting at floor(xmin); same for rows.
    float xmin = xb0 + fminf(0.0f, 31.0f * c) + fminf(0.0f, -31.0f * s);
    float ymin = yb0 + fminf(0.0f, 31.0f * s) + fminf(0.0f,  31.0f * c);

    int bx0 = min(max((int)floorf(xmin), 0), OUT_W - 1);
    int by0 = min(max((int)floorf(ymin), 0), OUT_H - 1);
    int bx_load = min(bx0, OUT_W - WPX);    // 46x46 window always in-image
    int by_load = min(by0, OUT_H - WROWS);

    const float* Ub = U + (size_t)b * (OUT_H * OUT_W * CHANS);
    const float* gb = Ub + ((size_t)by_load * OUT_W + bx_load) * CHANS;

    // ---- staging: 46 rows x 35 float4-units, lane-linear (coalesced) ----
    // unit u -> row r=u/35, cc=u%35; cc<34: dwords 4cc..4cc+3; cc==34: load
    // at dw=134 (overlap), write only dwords 136,137. All loads hoisted.
    float4 va[7];
#pragma unroll
    for (int it = 0; it < 7; ++it) {
        int u = tid + 256 * it;
        if (it < 6 || u < 46 * 35) {
            int r  = u / 35;
            int cc = u - r * 35;
            int dw = min(4 * cc, 134);
            va[it] = *(const float4*)(gb + (size_t)r * (OUT_W * CHANS) + dw);
        }
    }
#pragma unroll
    for (int it = 0; it < 7; ++it) {
        int u = tid + 256 * it;
        if (it < 6 || u < 46 * 35) {
            int r  = u / 35;
            int cc = u - r * 35;
            int dw = min(4 * cc, 134);
            int base = r * PITCH + dw;
            float4 v = va[it];
            if (cc < 34) {
                smf[base + 0] = v.x; smf[base + 1] = v.y;
                smf[base + 2] = v.z; smf[base + 3] = v.w;
            } else {
                smf[base + 2] = v.z; smf[base + 3] = v.w;
            }
        }
    }
    __syncthreads();

    // ---- compute: thread -> 4 consecutive px in one output row ----
    int il = tid >> 3;                  // 0..31
    int jb = (tid & 7) << 2;            // 0,4,...,28
    float xr = xb0 + c * (float)jb - s * (float)il;
    float yr = yb0 + s * (float)jb + c * (float)il;
    int Koff = by_load * PITCH + bx_load * 3;

    float o[12];
#pragma unroll
    for (int p = 0; p < 4; ++p) {
        float x = fmaf(c, (float)p, xr);
        float y = fmaf(s, (float)p, yr);

        int ix = __float2int_rd(x);
        int iy = __float2int_rd(y);
        float fx = x - (float)ix;
        float fy = y - (float)iy;

        int idx = iy * PITCH + ix * 3 - Koff;   // (iy-by)*139 + (ix-bx)*3
        idx = min(max(idx, 0), IDXMAX);         // v_med3; masked px safe

        const float* lp = smf + idx;            // single base, 6 ds_read2_b32
        float a0 = lp[0], a1 = lp[1], a2 = lp[2];          // (y0,x0)
        float c0 = lp[3], c1 = lp[4], c2 = lp[5];          // (y0,x1)
        float b0 = lp[PITCH + 0], b1 = lp[PITCH + 1], b2 = lp[PITCH + 2];
        float d0 = lp[PITCH + 3], d1 = lp[PITCH + 4], d2 = lp[PITCH + 5];

        float t0 = fmaf(fx, c0 - a0, a0);
        float t1 = fmaf(fx, c1 - a1, a1);
        float t2 = fmaf(fx, c2 - a2, a2);
        float u0 = fmaf(fx, d0 - b0, b0);
        float u1 = fmaf(fx, d1 - b1, b1);
        float u2 = fmaf(fx, d2 - b2, b2);
        float r0 = fmaf(fy, u0 - t0, t0);
        float r1 = fmaf(fy, u1 - t1, t1);
        float r2 = fmaf(fy, u2 - t2, t2);

        // Reference yields exactly 0 where clamped corners collapse
        // (x<0, x>=511, y<0, y>=511).
        bool valid = (x >= 0.0f) && (x < 511.0f) && (y >= 0.0f) && (y < 511.0f);
        o[p * 3 + 0] = valid ? r0 : 0.0f;
        o[p * 3 + 1] = valid ? r1 : 0.0f;
        o[p * 3 + 2] = valid ? r2 : 0.0f;
    }

    // 4 px = 48 B contiguous, 16B-aligned.
    float* po = out + (((size_t)b * OUT_H + (i0 + il)) * OUT_W + (j0 + jb)) * CHANS;
    ((float4*)po)[0] = make_float4(o[0], o[1], o[2],  o[3]);
    ((float4*)po)[1] = make_float4(o[4], o[5], o[6],  o[7]);
    ((float4*)po)[2] = make_float4(o[8], o[9], o[10], o[11]);
}

extern "C" void kernel_launch(void* const* d_in, const int* in_sizes, int n_in,
                              void* d_out, int out_size, void* d_ws, size_t ws_size,
                              hipStream_t stream) {
    const float* U     = (const float*)d_in[0];
    const float* theta = (const float*)d_in[1];
    float* out = (float*)d_out;

    int blocks = BATCH * (OUT_H / 32) * (OUT_W / 32);   // 16384
    st_bilinear_kernel<<<blocks, 256, 0, stream>>>(U, theta, out);
}

// Round 8
// 103.831 us; speedup vs baseline: 1.0404x; 1.0404x over previous
//
#include <hip/hip_runtime.h>
#include <hip/hip_fp16.h>

#define OUT_H 512
#define OUT_W 512
#define BATCH 64
#define CHANS 3

#define WROWS 48
#define WPX   48
#define SLOTP 64                    // 8B slots per LDS row (512B ≡ 0 mod 32 banks)
#define NSLOT (WROWS * SLOTP)       // 3072 slots = 24576 B -> 6 blocks/CU

__global__ __launch_bounds__(256) void st_bilinear_kernel(
    const float* __restrict__ U,      // [B, H, W, C] f32
    const float* __restrict__ theta,  // [B, 1]
    float* __restrict__ out)          // [B, H, W, C] f32
{
    // f16 pixel slots {c0,c1 | c2,0}. Diagonal remap col' = lx + (ly&15)
    // (max 62, +1 for x1 -> 63: no wrap). bank = 2*(lx + (ly&15)) mod 32:
    // both |c|~1 (lx-stride lanes) and |s|~1 (ly-stride lanes) regimes spread
    // across bank pairs -> <=2-way (free).
    __shared__ uint2 sm[NSLOT];

    // XCD-aware remap: give XCD k images [k*8, k*8+8) so each 3.1 MB image
    // stays resident in one XCD's 4 MB L2.
    int blk  = blockIdx.x;
    int lblk = (blk & 7) * 2048 + (blk >> 3);

    int b  = lblk >> 8;                 // image (uniform per block)
    int t  = lblk & 255;                // 16x16 tiles of 32x32 px
    int i0 = (t >> 4) << 5;
    int j0 = (t & 15) << 5;

    int tid = threadIdx.x;

    float tt = theta[__builtin_amdgcn_readfirstlane(b)];
    float s, c;
    __sincosf(tt, &s, &c);

    // x = xb0 + c*jl - s*il ; y = yb0 + s*jl + c*il  ((2/511)*255.5 == 1)
    const float scale = 2.0f / 511.0f;
    float gx0 = (float)j0 * scale - 1.0f;
    float gy0 = (float)i0 * scale - 1.0f;
    float xb0 = (c * gx0 - s * gy0 + 1.0f) * 255.5f;
    float yb0 = (s * gx0 + c * gy0 + 1.0f) * 255.5f;

    // Source bbox of the 32x32 tile: span 31(|c|+|s|)+2 <= 46 -> 48 window.
    float xmin = xb0 + fminf(0.0f, 31.0f * c) + fminf(0.0f, -31.0f * s);
    float ymin = yb0 + fminf(0.0f, 31.0f * s) + fminf(0.0f,  31.0f * c);

    int bx0 = min(max((int)floorf(xmin), 0), OUT_W - 1);
    int by0 = min(max((int)floorf(ymin), 0), OUT_H - 1);
    int bx_load = min(bx0, OUT_W - WPX);    // 48x48 window always in-image
    int by_load = min(by0, OUT_H - WROWS);

    const float* Ub = U + (size_t)b * (OUT_H * OUT_W * CHANS);
    const float* gb = Ub + ((size_t)by_load * OUT_W + bx_load) * CHANS;

    // ---- staging: 2304 px, 9 px/thread, lane-linear (12B stride, coalesced),
    // one ds_write_b64 per px. Loads hoisted to cover HBM latency. ----
    float2 lc01[9];
    float  lc2[9];
#pragma unroll
    for (int k = 0; k < 9; ++k) {
        unsigned q = (unsigned)tid + 256u * k;      // 0..2303
        unsigned r  = q / 48u;                      // magic-mul
        unsigned lx = q - r * 48u;
        const float* p = gb + (size_t)r * (OUT_W * CHANS) + lx * 3u;
        lc01[k] = *(const float2*)p;
        lc2[k]  = p[2];
    }
#pragma unroll
    for (int k = 0; k < 9; ++k) {
        unsigned q = (unsigned)tid + 256u * k;
        unsigned r  = q / 48u;
        unsigned lx = q - r * 48u;
        __half2 h01 = __floats2half2_rn(lc01[k].x, lc01[k].y);
        __half2 h2  = __floats2half2_rn(lc2[k], 0.0f);
        uint2 v;
        v.x = *(const unsigned int*)&h01;
        v.y = *(const unsigned int*)&h2;
        sm[r * SLOTP + lx + (r & 15u)] = v;         // ds_write_b64
    }
    __syncthreads();

    // ---- compute: thread -> 4 consecutive px in one output row ----
    int il = tid >> 3;                  // 0..31
    int jb = (tid & 7) << 2;            // 0,4,...,28
    float xr = xb0 + c * (float)jb - s * (float)il;
    float yr = yb0 + s * (float)jb + c * (float)il;

    float o[12];
#pragma unroll
    for (int p = 0; p < 4; ++p) {
        float x = fmaf(c, (float)p, xr);
        float y = fmaf(s, (float)p, yr);

        int ix = __float2int_rd(x);
        int iy = __float2int_rd(y);
        float fx = x - (float)ix;
        float fy = y - (float)iy;

        // clamp to window so masked px read in-array (v_med3 each)
        int lx = min(max(ix - bx_load, 0), WPX - 2);     // 0..46
        int ly = min(max(iy - by_load, 0), WROWS - 2);   // 0..46

        int p0 = ly * SLOTP + lx + (ly & 15);            // row y0, cols x0,x1
        int p1 = (ly + 1) * SLOTP + lx + ((ly + 1) & 15);

        uint2 A0 = sm[p0], A1 = sm[p0 + 1];              // ds_read2_b64
        uint2 B0 = sm[p1], B1 = sm[p1 + 1];              // ds_read2_b64

        __half2 fx2 = __float2half2_rn(fx);
        __half2 fy2 = __float2half2_rn(fy);

        __half2 a01 = *(const __half2*)&A0.x, a2 = *(const __half2*)&A0.y;
        __half2 c01 = *(const __half2*)&A1.x, c2 = *(const __half2*)&A1.y;
        __half2 b01 = *(const __half2*)&B0.x, b2 = *(const __half2*)&B0.y;
        __half2 d01 = *(const __half2*)&B1.x, d2 = *(const __half2*)&B1.y;

        __half2 t01 = __hfma2(fx2, __hsub2(c01, a01), a01);   // top lerp
        __half2 t2  = __hfma2(fx2, __hsub2(c2,  a2),  a2);
        __half2 u01 = __hfma2(fx2, __hsub2(d01, b01), b01);   // bottom lerp
        __half2 u2  = __hfma2(fx2, __hsub2(d2,  b2),  b2);
        __half2 r01 = __hfma2(fy2, __hsub2(u01, t01), t01);   // vertical
        __half2 r2  = __hfma2(fy2, __hsub2(u2,  t2),  t2);

        // Reference yields exactly 0 where clamped corners collapse
        // (x<0, x>=511, y<0, y>=511).
        bool valid = (x >= 0.0f) && (x < 511.0f) && (y >= 0.0f) && (y < 511.0f);
        o[p * 3 + 0] = valid ? __low2float(r01)  : 0.0f;
        o[p * 3 + 1] = valid ? __high2float(r01) : 0.0f;
        o[p * 3 + 2] = valid ? __low2float(r2)   : 0.0f;
    }

    // 4 px = 48 B contiguous, 16B-aligned.
    float* po = out + (((size_t)b * OUT_H + (i0 + il)) * OUT_W + (j0 + jb)) * CHANS;
    ((float4*)po)[0] = make_float4(o[0], o[1], o[2],  o[3]);
    ((float4*)po)[1] = make_float4(o[4], o[5], o[6],  o[7]);
    ((float4*)po)[2] = make_float4(o[8], o[9], o[10], o[11]);
}

extern "C" void kernel_launch(void* const* d_in, const int* in_sizes, int n_in,
                              void* d_out, int out_size, void* d_ws, size_t ws_size,
                              hipStream_t stream) {
    const float* U     = (const float*)d_in[0];
    const float* theta = (const float*)d_in[1];
    float* out = (float*)d_out;

    int blocks = BATCH * (OUT_H / 32) * (OUT_W / 32);   // 16384
    st_bilinear_kernel<<<blocks, 256, 0, stream>>>(U, theta, out);
}

// Round 9
// 101.737 us; speedup vs baseline: 1.0618x; 1.0206x over previous
//
#include <hip/hip_runtime.h>
#include <hip/hip_fp16.h>

#define OUT_H 512
#define OUT_W 512
#define BATCH 64
#define CHANS 3

#define WROWS 48
#define WPX   48
#define PITCH 49                 // dword slots per LDS row; odd -> gcd(49,32)=1, all banks
#define PLANE (WROWS * PITCH)    // 2352 dwords = 9408 B per plane
#define IDXMAX (PLANE - PITCH - 2)   // 2301: max read = 2301+49+1 = 2351 < 2352

__global__ __launch_bounds__(256) void st_bilinear_kernel(
    const float* __restrict__ U,      // [B, H, W, C] f32
    const float* __restrict__ theta,  // [B, 1]
    float* __restrict__ out)          // [B, H, W, C] f32
{
    // SoA f16 planes, 4B granular: smA[px] = half2{c0,c1}, smB[px] = half2{c2,0}.
    // Odd pitch 49 -> source-row stride hits all 32 banks in every rotation
    // regime; 4B slots -> wave64 min 2 lanes/bank (free).
    __shared__ __align__(16) unsigned int smA[PLANE];
    __shared__ __align__(16) unsigned int smB[PLANE];

    // XCD-aware remap: give XCD k images [k*8, k*8+8) so each 3.1 MB image
    // stays resident in one XCD's 4 MB L2.
    int blk  = blockIdx.x;
    int lblk = (blk & 7) * 2048 + (blk >> 3);

    int b  = lblk >> 8;                 // image (uniform per block)
    int t  = lblk & 255;                // 16x16 tiles of 32x32 px
    int i0 = (t >> 4) << 5;
    int j0 = (t & 15) << 5;

    int tid = threadIdx.x;

    float tt = theta[__builtin_amdgcn_readfirstlane(b)];
    float s, c;
    __sincosf(tt, &s, &c);

    // x = xb0 + c*jl - s*il ; y = yb0 + s*jl + c*il  ((2/511)*255.5 == 1)
    const float scale = 2.0f / 511.0f;
    float gx0 = (float)j0 * scale - 1.0f;
    float gy0 = (float)i0 * scale - 1.0f;
    float xb0 = (c * gx0 - s * gy0 + 1.0f) * 255.5f;
    float yb0 = (s * gx0 + c * gy0 + 1.0f) * 255.5f;

    // Source bbox of the 32x32 tile: span 31(|c|+|s|)+2 <= 46 -> 48 window.
    float xmin = xb0 + fminf(0.0f, 31.0f * c) + fminf(0.0f, -31.0f * s);
    float ymin = yb0 + fminf(0.0f, 31.0f * s) + fminf(0.0f,  31.0f * c);

    int bx0 = min(max((int)floorf(xmin), 0), OUT_W - 1);
    int by0 = min(max((int)floorf(ymin), 0), OUT_H - 1);
    int bx_load = min(bx0, OUT_W - WPX);    // 48x48 window always in-image
    int by_load = min(by0, OUT_H - WROWS);

    const float* Ub = U + (size_t)b * (OUT_H * OUT_W * CHANS);
    const float* gb = Ub + ((size_t)by_load * OUT_W + bx_load) * CHANS;

    // ---- staging: 2304 px, 9 px/thread, lane-linear (12B stride, coalesced),
    // loads hoisted; writes are stride-1 ds_write_b32 (zero bank conflict). ----
    float2 lc01[9];
    float  lc2[9];
#pragma unroll
    for (int k = 0; k < 9; ++k) {
        unsigned q = (unsigned)tid + 256u * k;      // 0..2303
        unsigned r  = q / 48u;                      // magic-mul
        unsigned lx = q - r * 48u;
        const float* p = gb + (size_t)r * (OUT_W * CHANS) + lx * 3u;
        lc01[k] = *(const float2*)p;
        lc2[k]  = p[2];
    }
#pragma unroll
    for (int k = 0; k < 9; ++k) {
        unsigned q = (unsigned)tid + 256u * k;
        unsigned r  = q / 48u;
        unsigned lx = q - r * 48u;
        unsigned slot = r * PITCH + lx;             // lane-stride ~1
        __half2 h01 = __floats2half2_rn(lc01[k].x, lc01[k].y);
        __half2 h2  = __floats2half2_rn(lc2[k], 0.0f);
        smA[slot] = *(const unsigned int*)&h01;
        smB[slot] = *(const unsigned int*)&h2;
    }
    __syncthreads();

    // ---- compute: thread -> 4 consecutive px in one output row ----
    int il = tid >> 3;                  // 0..31
    int jb = (tid & 7) << 2;            // 0,4,...,28
    float xr = xb0 + c * (float)jb - s * (float)il;
    float yr = yb0 + s * (float)jb + c * (float)il;
    int Koff = by_load * PITCH + bx_load;

    float o[12];
#pragma unroll
    for (int p = 0; p < 4; ++p) {
        float x = fmaf(c, (float)p, xr);
        float y = fmaf(s, (float)p, yr);

        int ix = __float2int_rd(x);
        int iy = __float2int_rd(y);
        float fx = x - (float)ix;
        float fy = y - (float)iy;

        int idx = iy * PITCH + ix - Koff;       // (iy-by)*49 + (ix-bx)
        idx = min(max(idx, 0), IDXMAX);         // v_med3; masked px read junk safely

        // 4 x ds_read2_b32: A{0,1}, A{49,50}, B{0,1}, B{49,50}
        unsigned iA0 = smA[idx],         iA1 = smA[idx + 1];
        unsigned iA2 = smA[idx + PITCH], iA3 = smA[idx + PITCH + 1];
        unsigned iB0 = smB[idx],         iB1 = smB[idx + 1];
        unsigned iB2 = smB[idx + PITCH], iB3 = smB[idx + PITCH + 1];

        __half2 fx2 = __float2half2_rn(fx);
        __half2 fy2 = __float2half2_rn(fy);
        __half2 a01 = *(const __half2*)&iA0, c01 = *(const __half2*)&iA1;
        __half2 b01 = *(const __half2*)&iA2, d01 = *(const __half2*)&iA3;
        __half2 a2  = *(const __half2*)&iB0, c2  = *(const __half2*)&iB1;
        __half2 b2  = *(const __half2*)&iB2, d2  = *(const __half2*)&iB3;

        __half2 t01 = __hfma2(fx2, __hsub2(c01, a01), a01);   // top lerp
        __half2 t2  = __hfma2(fx2, __hsub2(c2,  a2),  a2);
        __half2 u01 = __hfma2(fx2, __hsub2(d01, b01), b01);   // bottom lerp
        __half2 u2  = __hfma2(fx2, __hsub2(d2,  b2),  b2);
        __half2 r01 = __hfma2(fy2, __hsub2(u01, t01), t01);   // vertical
        __half2 r2  = __hfma2(fy2, __hsub2(u2,  t2),  t2);

        // Reference yields exactly 0 where clamped corners collapse
        // (x<0, x>=511, y<0, y>=511).
        bool valid = (x >= 0.0f) && (x < 511.0f) && (y >= 0.0f) && (y < 511.0f);
        o[p * 3 + 0] = valid ? __low2float(r01)  : 0.0f;
        o[p * 3 + 1] = valid ? __high2float(r01) : 0.0f;
        o[p * 3 + 2] = valid ? __low2float(r2)   : 0.0f;
    }

    // 4 px = 48 B contiguous, 16B-aligned.
    float* po = out + (((size_t)b * OUT_H + (i0 + il)) * OUT_W + (j0 + jb)) * CHANS;
    ((float4*)po)[0] = make_float4(o[0], o[1], o[2],  o[3]);
    ((float4*)po)[1] = make_float4(o[4], o[5], o[6],  o[7]);
    ((float4*)po)[2] = make_float4(o[8], o[9], o[10], o[11]);
}

extern "C" void kernel_launch(void* const* d_in, const int* in_sizes, int n_in,
                              void* d_out, int out_size, void* d_ws, size_t ws_size,
                              hipStream_t stream) {
    const float* U     = (const float*)d_in[0];
    const float* theta = (const float*)d_in[1];
    float* out = (float*)d_out;

    int blocks = BATCH * (OUT_H / 32) * (OUT_W / 32);   // 16384
    st_bilinear_kernel<<<blocks, 256, 0, stream>>>(U, theta, out);
}